// Round 15
// baseline (376.535 us; speedup 1.0000x reference)
//
#include <hip/hip_runtime.h>

typedef unsigned short ushort_t;
typedef unsigned int   uint_t;
typedef unsigned char  uchar_t;
typedef __attribute__((ext_vector_type(8))) __bf16 bf16x8;
typedef __attribute__((ext_vector_type(4))) float   f32x4;

// bf16 helpers (stored bf16, computed f32)
__device__ __forceinline__ float bl(uint_t u){ return __uint_as_float(u<<16); }
__device__ __forceinline__ float bh(uint_t u){ return __uint_as_float(u & 0xffff0000u); }
__device__ __forceinline__ ushort_t f2b(float f){
  uint_t x = __float_as_uint(f);
  return (ushort_t)((x + 0x7fffu + ((x>>16)&1u)) >> 16);   // RTNE
}
__device__ __forceinline__ uint_t pack2(float a, float b){
  return (uint_t)f2b(a) | ((uint_t)f2b(b) << 16);
}

// DPP rotate-reduce over each 16-lane row (VALU-rate, no DS ops)
__device__ __forceinline__ float row_reduce16(float p){
  float t;
  t = __uint_as_float(__builtin_amdgcn_update_dpp(0, __float_as_uint(p), 0x121, 0xf, 0xf, true)); p += t; // row_ror:1
  t = __uint_as_float(__builtin_amdgcn_update_dpp(0, __float_as_uint(p), 0x122, 0xf, 0xf, true)); p += t; // row_ror:2
  t = __uint_as_float(__builtin_amdgcn_update_dpp(0, __float_as_uint(p), 0x124, 0xf, 0xf, true)); p += t; // row_ror:4
  t = __uint_as_float(__builtin_amdgcn_update_dpp(0, __float_as_uint(p), 0x128, 0xf, 0xf, true)); p += t; // row_ror:8
  return p;
}

#define NBK 128          // max dst buckets (bucket = dst >> 9)
#define PBLK 256         // partition blocks

// ------- FUSE_A: blocks [0,48): wswz | [48,304): hist | 304: zero pooled ----
__global__ __launch_bounds__(256) void k_fuse_a(
    const float* __restrict__ Wsrc, const float* __restrict__ Wdst,
    ushort_t* __restrict__ WB,
    const int* __restrict__ dst, int* __restrict__ bhist, int E, int epb,
    float* __restrict__ pooled)
{
  int blk = blockIdx.x;
  if (blk < 48) {                    // weight pre-swizzle (12288 threads exact)
    int t = blk*256 + threadIdx.x;
    int l = t >> 12;
    int rem = t & 4095;
    int ct = rem >> 8;
    int kc = (rem >> 6) & 3;
    int lane = rem & 63;
    int n = ct*16 + (lane & 15);
    int kbase = kc*32 + (lane >> 4)*8;
    const float* Wp; int nn;
    if (n < 128) { Wp = Wsrc + l*16384; nn = n; }
    else         { Wp = Wdst + l*16384; nn = n - 128; }
    uint4 o;
    o.x = pack2(Wp[(kbase+0)*128+nn], Wp[(kbase+1)*128+nn]);
    o.y = pack2(Wp[(kbase+2)*128+nn], Wp[(kbase+3)*128+nn]);
    o.z = pack2(Wp[(kbase+4)*128+nn], Wp[(kbase+5)*128+nn]);
    o.w = pack2(Wp[(kbase+6)*128+nn], Wp[(kbase+7)*128+nn]);
    *(uint4*)&WB[(size_t)t * 8] = o;
  } else if (blk < 304) {            // bucket histogram
    __shared__ int lh[NBK];
    int b2 = blk - 48, t = threadIdx.x;
    if (t < NBK) lh[t] = 0;
    __syncthreads();
    int s = b2*epb, e = s + epb; if (e > E) e = E;
    for (int i = s + t; i < e; i += 256)
      atomicAdd(&lh[dst[i] >> 9], 1);
    __syncthreads();
    if (t < NBK) bhist[t*PBLK + b2] = lh[t];   // bucket-major
  } else {
    if (threadIdx.x < 128) pooled[threadIdx.x] = 0.f;
  }
}

// ------- CSR stage 2: scan (bucket,block) hist -> gOff, bucketOff -----------
__global__ __launch_bounds__(1024) void k_scan2(
    const int* __restrict__ bhist, int* __restrict__ gOff,
    int* __restrict__ bucketOff, int E)
{
  __shared__ int sums[1024];
  int tid = threadIdx.x;
  int s0 = tid * 32;                 // 32768 entries, 32 per thread
  int local = 0;
  #pragma unroll
  for (int i = 0; i < 32; ++i) local += bhist[s0 + i];
  sums[tid] = local;
  __syncthreads();
  for (int off = 1; off < 1024; off <<= 1) {
    int v = (tid >= off) ? sums[tid - off] : 0;
    __syncthreads();
    sums[tid] += v;
    __syncthreads();
  }
  int run = (tid == 0) ? 0 : sums[tid - 1];
  #pragma unroll
  for (int i = 0; i < 32; ++i) { gOff[s0 + i] = run; run += bhist[s0 + i]; }
  __syncthreads();
  if (tid < NBK) bucketOff[tid] = gOff[tid*PBLK];
  if (tid == NBK) bucketOff[NBK] = E;
}

// ------- FUSE_B: blocks [0,PBLK): partition | rest: input GEMM --------------
__global__ __launch_bounds__(256) void k_fuse_b(
    const int* __restrict__ src, const int* __restrict__ dst,
    const int* __restrict__ gOff, uint_t* __restrict__ part, int E, int epb,
    const float* __restrict__ nf, const float* __restrict__ W,
    const float* __restrict__ b, ushort_t* __restrict__ HB, int N)
{
  __shared__ int loff[NBK];
  __shared__ float sA[64*64];
  if (blockIdx.x < PBLK) {           // edge partition into dst-buckets
    int blk = blockIdx.x, t = threadIdx.x;
    if (t < NBK) loff[t] = gOff[t*PBLK + blk];
    __syncthreads();
    int s = blk*epb, e = s + epb; if (e > E) e = E;
    for (int i = s + t; i < e; i += 256) {
      int d = dst[i];
      int bb = d >> 9;
      int p = atomicAdd(&loff[bb], 1);
      part[p] = (uint_t)src[i] | ((uint_t)(d & 511) << 16);
    }
  } else {                           // HB = bf16( nf @ W_in + b_in )
    int row0 = (blockIdx.x - PBLK) * 64;
    int tid = threadIdx.x;
    {
      int q = tid;
      #pragma unroll
      for (int j = 0; j < 4; ++j, q += 256) {
        int r = q >> 4;
        int c = (q & 15) << 2;
        float4 v = make_float4(0.f,0.f,0.f,0.f);
        if (row0 + r < N) v = *(const float4*)&nf[(size_t)(row0 + r)*64 + c];
        *(float4*)&sA[r*64 + c] = v;
      }
    }
    __syncthreads();
    int cg = tid & 15, rg = tid >> 4;
    int c0 = cg * 8;
    float acc[4][8];
    #pragma unroll
    for (int i = 0; i < 4; ++i)
      #pragma unroll
      for (int j = 0; j < 8; ++j) acc[i][j] = 0.f;
    for (int k = 0; k < 64; ++k) {
      float4 wa = *(const float4*)&W[k*128 + c0];
      float4 wb = *(const float4*)&W[k*128 + c0 + 4];
      float w[8] = {wa.x,wa.y,wa.z,wa.w,wb.x,wb.y,wb.z,wb.w};
      float hv[4];
      #pragma unroll
      for (int i = 0; i < 4; ++i) hv[i] = sA[(rg*4 + i)*64 + k];
      #pragma unroll
      for (int i = 0; i < 4; ++i)
        #pragma unroll
        for (int j = 0; j < 8; ++j) acc[i][j] += hv[i]*w[j];
    }
    float4 b1 = *(const float4*)&b[c0];
    float4 b2 = *(const float4*)&b[c0 + 4];
    float bb[8] = {b1.x,b1.y,b1.z,b1.w,b2.x,b2.y,b2.z,b2.w};
    #pragma unroll
    for (int i = 0; i < 4; ++i) {
      int row = row0 + rg*4 + i;
      if (row < N) {
        uint4 hb;
        hb.x = pack2(acc[i][0]+bb[0], acc[i][1]+bb[1]);
        hb.y = pack2(acc[i][2]+bb[2], acc[i][3]+bb[3]);
        hb.z = pack2(acc[i][4]+bb[4], acc[i][5]+bb[5]);
        hb.w = pack2(acc[i][6]+bb[6], acc[i][7]+bb[7]);
        *(uint4*)&HB[(size_t)row*128 + c0] = hb;
      }
    }
  }
}

// ------- CSR stage 4: count+scan+rowp+place; store u16 src row indices ------
__global__ __launch_bounds__(512) void k_csr(
    const uint_t* __restrict__ part, const int* __restrict__ bucketOff,
    int* __restrict__ rowp, ushort_t* __restrict__ csrc16, int N, int E)
{
  __shared__ int lcnt[512];
  __shared__ int lpos[512];
  int b = blockIdx.x, t = threadIdx.x;
  int base = b << 9;
  int cnt = N - base; if (cnt > 512) cnt = 512;
  lcnt[t] = 0;
  __syncthreads();
  int s = bucketOff[b], e = bucketOff[b + 1];
  for (int i = s + t; i < e; i += 512)
    atomicAdd(&lcnt[part[i] >> 16], 1);
  __syncthreads();
  int v = lcnt[t];
  lpos[t] = v;
  __syncthreads();
  for (int off = 1; off < 512; off <<= 1) {       // inclusive scan
    int u = (t >= off) ? lpos[t - off] : 0;
    __syncthreads();
    lpos[t] += u;
    __syncthreads();
  }
  int rp = s + lpos[t] - v;                       // exclusive prefix + bucket base
  if (t < cnt) rowp[base + t] = rp;
  if (b == 0 && t == 0) rowp[N] = E;
  __syncthreads();
  lpos[t] = rp;
  __syncthreads();
  for (int i = s + t; i < e; i += 512) {
    uint_t pr = part[i];
    int p = atomicAdd(&lpos[pr >> 16], 1);
    csrc16[p] = (ushort_t)(pr & 0xffffu);         // row index; <<7 at use site
  }
}

// ------- layer GEMM via MFMA: FS8 / FD8 = fp8( HB @ W + b ), symmetric ------
__global__ __launch_bounds__(256) void k_gemm_mfma(
    const ushort_t* __restrict__ HB, const ushort_t* __restrict__ WB,
    const float* __restrict__ bsrc, const float* __restrict__ bdst,
    uchar_t* __restrict__ FS8, uchar_t* __restrict__ FD8, int N)
{
  int m0 = blockIdx.x * 32;
  int tid = threadIdx.x;
  int w = tid >> 6, lane = tid & 63;
  int lrow = lane & 15, lk = lane >> 4;

  bf16x8 a[2][4];
  #pragma unroll
  for (int rt = 0; rt < 2; ++rt) {
    int row = m0 + rt*16 + lrow;
    if (row > N-1) row = N-1;
    #pragma unroll
    for (int kc = 0; kc < 4; ++kc)
      a[rt][kc] = *(const bf16x8*)&HB[(size_t)row*128 + kc*32 + lk*8];
  }

  #pragma unroll
  for (int c = 0; c < 4; ++c) {
    int ct = w*4 + c;
    int n = ct*16 + lrow;
    bf16x8 bfr[4];
    #pragma unroll
    for (int kc = 0; kc < 4; ++kc)
      bfr[kc] = *(const bf16x8*)&WB[((size_t)(ct*4 + kc)*64 + lane) * 8];
    int nn = n & 127;
    uchar_t* OUT = (ct < 8) ? FS8 : FD8;
    float bias = (ct < 8) ? bsrc[nn] : bdst[nn];
    #pragma unroll
    for (int rt = 0; rt < 2; ++rt) {
      f32x4 acc = {0.f, 0.f, 0.f, 0.f};
      #pragma unroll
      for (int kc = 0; kc < 4; ++kc)
        acc = __builtin_amdgcn_mfma_f32_16x16x32_bf16(a[rt][kc], bfr[kc], acc, 0, 0, 0);
      int r = m0 + rt*16 + lk*4;        // C/D: col=lane&15, row=(lane>>4)*4+reg
      int w01 = __builtin_amdgcn_cvt_pk_fp8_f32(acc[0]+bias, acc[1]+bias, 0, false);
      int w23 = __builtin_amdgcn_cvt_pk_fp8_f32(acc[2]+bias, acc[3]+bias, 0, false);
      if (r     < N) OUT[(size_t)(r    )*128 + nn] = (uchar_t)(w01);
      if (r + 1 < N) OUT[(size_t)(r + 1)*128 + nn] = (uchar_t)(w01 >> 8);
      if (r + 2 < N) OUT[(size_t)(r + 2)*128 + nn] = (uchar_t)(w23);
      if (r + 3 < N) OUT[(size_t)(r + 3)*128 + nn] = (uchar_t)(w23 >> 8);
    }
  }
}

// ------- fused edge aggregate + softmax + residual + LN + ReLU ---------------
// PERSISTENT grid-stride version of the r14 body: 2048 blocks x 4 waves stay
// resident; each wave loops over nodes with stride (gridDim*4). Attn-derived
// constants hoisted out of the node loop.
__global__ __launch_bounds__(256) void k_edge(
    const uchar_t* __restrict__ FS8, const uchar_t* __restrict__ FD8,
    ushort_t* __restrict__ HB, float* __restrict__ H,
    const int* __restrict__ rowp, const ushort_t* __restrict__ csrc16,
    const float* __restrict__ attn, const float* __restrict__ lng,
    const float* __restrict__ lnb, int last, int N)
{
  int lane = threadIdx.x & 63;
  int wid  = threadIdx.x >> 6;
  int g = lane >> 4;                 // edge slot within quad (== DPP row id)
  int c = lane & 15;                 // channel chunk
  int cb = c << 3;                   // channel base (fp8 byte offset)
  int stride = gridDim.x * 4;

  float av6[8], av4[8];
  {
    float4 a1 = *(const float4*)&attn[cb];
    float4 a2 = *(const float4*)&attn[cb + 4];
    float aa[8] = {a1.x,a1.y,a1.z,a1.w,a2.x,a2.y,a2.z,a2.w};
    #pragma unroll
    for (int k = 0; k < 8; ++k) {
      av6[k] = aa[k] * 0.865617024f;   // 0.6 * log2(e)
      av4[k] = aa[k] * 0.577078016f;   // 0.4 * log2(e)
    }
  }
  float4 g1 = *(const float4*)&lng[cb];
  float4 g2 = *(const float4*)&lng[cb + 4];
  float4 be1 = *(const float4*)&lnb[cb];
  float4 be2 = *(const float4*)&lnb[cb + 4];
  float gv[8] = {g1.x,g1.y,g1.z,g1.w,g2.x,g2.y,g2.z,g2.w};
  float bv[8] = {be1.x,be1.y,be1.z,be1.w,be2.x,be2.y,be2.z,be2.w};

  for (int node0 = blockIdx.x * 4 + wid; node0 < N; node0 += stride) {
    int node = __builtin_amdgcn_readfirstlane(node0);

    float fdv[8];
    {
      uint2 fdu = *(const uint2*)((const char*)FD8 + node*128 + cb);
      auto f01 = __builtin_amdgcn_cvt_pk_f32_fp8((int)fdu.x, false);
      auto f23 = __builtin_amdgcn_cvt_pk_f32_fp8((int)fdu.x, true);
      auto f45 = __builtin_amdgcn_cvt_pk_f32_fp8((int)fdu.y, false);
      auto f67 = __builtin_amdgcn_cvt_pk_f32_fp8((int)fdu.y, true);
      fdv[0]=f01[0]; fdv[1]=f01[1]; fdv[2]=f23[0]; fdv[3]=f23[1];
      fdv[4]=f45[0]; fdv[5]=f45[1]; fdv[6]=f67[0]; fdv[7]=f67[1];
    }
    int beg = __builtin_amdgcn_readfirstlane(rowp[node]);
    int end = __builtin_amdgcn_readfirstlane(rowp[node + 1]);   // deg >= 1
    int deg = end - beg;
    int npair = deg >> 4, ntail = deg & 15;
    int tb = beg + (npair << 4);
    int endm1 = end - 1;

    float den = 0.f;
    float acc[8];
    #pragma unroll
    for (int k = 0; k < 8; ++k) acc[k] = 0.f;

    uint2 a0,a1q,a2q,a3q, b0,b1q,b2q,b3q, t0,t1q,t2q,t3q;

    #define PREF(bu0, bu1, kb) {                                              \
      int s0 = ((int)csrc16[(kb) + g]) << 7;                                  \
      int s1 = ((int)csrc16[(kb) + 4 + g]) << 7;                              \
      bu0 = *(const uint2*)((const char*)FS8 + s0 + cb);                      \
      bu1 = *(const uint2*)((const char*)FS8 + s1 + cb);                      \
    }

    #define PREFT(bu0, bu1, kb) {                                             \
      int i0 = (kb) + g;     i0 = (i0 < endm1) ? i0 : endm1;                  \
      int i1 = (kb) + 4 + g; i1 = (i1 < endm1) ? i1 : endm1;                  \
      bu0 = *(const uint2*)((const char*)FS8 + (((int)csrc16[i0]) << 7) + cb);\
      bu1 = *(const uint2*)((const char*)FS8 + (((int)csrc16[i1]) << 7) + cb);\
    }

    #define QM(u, MASKED, kbq) {                                              \
      float cf[8];                                                            \
      { auto p01 = __builtin_amdgcn_cvt_pk_f32_fp8((int)(u).x, false);        \
        auto p23 = __builtin_amdgcn_cvt_pk_f32_fp8((int)(u).x, true);         \
        auto p45 = __builtin_amdgcn_cvt_pk_f32_fp8((int)(u).y, false);        \
        auto p67 = __builtin_amdgcn_cvt_pk_f32_fp8((int)(u).y, true);         \
        cf[0]=p01[0]; cf[1]=p01[1]; cf[2]=p23[0]; cf[3]=p23[1];               \
        cf[4]=p45[0]; cf[5]=p45[1]; cf[6]=p67[0]; cf[7]=p67[1]; }             \
      float p = 0.f;                                                          \
      _Pragma("unroll")                                                       \
      for (int k = 0; k < 8; ++k) {                                           \
        float x = cf[k] + fdv[k];                                             \
        p = fmaf(x, av6[k], p);                                               \
        p = fmaf(fabsf(x), av4[k], p);                                        \
      }                                                                       \
      p = row_reduce16(p);                                                    \
      float ex = __builtin_amdgcn_exp2f(p);                                   \
      if (MASKED) ex = ((kbq) + g < end) ? ex : 0.f;                          \
      den += ex;                                                              \
      _Pragma("unroll")                                                       \
      for (int k = 0; k < 8; ++k) acc[k] = fmaf(ex, cf[k], acc[k]);           \
    }

    if (ntail) { PREFT(t0, t1q, tb) PREFT(t2q, t3q, tb + 8) }
    if (npair) {
      PREF(a0, a1q, beg) PREF(a2q, a3q, beg + 8)
      int rem2 = npair, kb = beg + 16;
      for (;;) {
        if (rem2 > 1) { PREF(b0, b1q, kb) PREF(b2q, b3q, kb + 8) }
        QM(a0, 0, 0) QM(a1q, 0, 0) QM(a2q, 0, 0) QM(a3q, 0, 0)
        if (--rem2 == 0) break;
        kb += 16;
        if (rem2 > 1) { PREF(a0, a1q, kb) PREF(a2q, a3q, kb + 8) }
        QM(b0, 0, 0) QM(b1q, 0, 0) QM(b2q, 0, 0) QM(b3q, 0, 0)
        if (--rem2 == 0) break;
        kb += 16;
      }
    }
    if (ntail) {
      QM(t0, 1, tb) QM(t1q, 1, tb + 4) QM(t2q, 1, tb + 8) QM(t3q, 1, tb + 12)
    }
    #undef PREF
    #undef PREFT
    #undef QM

    // combine the 4 edge-slot partials (cross-row shuffles, once per node)
    den += __shfl_xor(den, 16); den += __shfl_xor(den, 32);
    #pragma unroll
    for (int k = 0; k < 8; ++k) {
      acc[k] += __shfl_xor(acc[k], 16);
      acc[k] += __shfl_xor(acc[k], 32);
    }
    float rden = 1.f / den;            // deg >= 1 -> den > 0

    // residual + LN + ReLU (each lane owns its 8 channels; groups redundant)
    float x[8];
    {
      uint4 hu = *(const uint4*)((const char*)HB + node*256 + (cb << 1));
      float hb[8] = {bl(hu.x),bh(hu.x),bl(hu.y),bh(hu.y),
                     bl(hu.z),bh(hu.z),bl(hu.w),bh(hu.w)};
      #pragma unroll
      for (int k = 0; k < 8; ++k) x[k] = 2.f*hb[k] + acc[k]*rden;
    }
    float s = 0.f;
    #pragma unroll
    for (int k = 0; k < 8; ++k) s += x[k];
    s = row_reduce16(s);
    float mean = s * (1.f/128.f);
    float v = 0.f;
    #pragma unroll
    for (int k = 0; k < 8; ++k) { x[k] -= mean; v += x[k]*x[k]; }
    v = row_reduce16(v);
    float rs = rsqrtf(v * (1.f/128.f) + 1e-5f);
    float y[8];
    #pragma unroll
    for (int k = 0; k < 8; ++k) y[k] = fmaxf(x[k]*rs*gv[k] + bv[k], 0.f);

    if (lane < 16) {                   // one group writes
      if (last) {
        float4 o1 = make_float4(y[0],y[1],y[2],y[3]);
        float4 o2 = make_float4(y[4],y[5],y[6],y[7]);
        *(float4*)((char*)H + node*512 + (cb << 2))      = o1;
        *(float4*)((char*)H + node*512 + (cb << 2) + 16) = o2;
      } else {
        uint4 o;
        o.x = pack2(y[0],y[1]); o.y = pack2(y[2],y[3]);
        o.z = pack2(y[4],y[5]); o.w = pack2(y[6],y[7]);
        *(uint4*)((char*)HB + node*256 + (cb << 1)) = o;
      }
    }
  }
}

// ---------------- pooled mean partials ----------------
__global__ __launch_bounds__(128) void k_pool(const float* __restrict__ H,
                                              float* __restrict__ pooled, int N){
  int c = threadIdx.x;
  float s = 0.f;
  for (int r = blockIdx.x; r < N; r += gridDim.x) s += H[(size_t)r*128 + c];
  atomicAdd(&pooled[c], s);
}

// ---------------- final head ----------------
__global__ __launch_bounds__(256) void k_final(
    const float* __restrict__ gf, const float* __restrict__ pooled,
    const float* __restrict__ Wg, const float* __restrict__ bg,
    const float* __restrict__ Wf1, const float* __restrict__ bf1,
    const float* __restrict__ Wf2, const float* __restrict__ bf2v,
    float* __restrict__ out, float inv_n)
{
  __shared__ float comb[256];
  __shared__ float t1[128];
  int tid = threadIdx.x;
  if (tid < 128) {
    comb[tid] = pooled[tid] * inv_n;
  } else {
    int c = tid - 128;
    float s = bg[c];
    for (int k = 0; k < 32; ++k) s += gf[k] * Wg[k*128 + c];
    comb[128 + c] = s;
  }
  __syncthreads();
  if (tid < 128) {
    float s = bf1[tid];
    for (int k = 0; k < 256; ++k) s += comb[k] * Wf1[k*128 + tid];
    t1[tid] = fmaxf(s, 0.f);
  }
  __syncthreads();
  if (tid < 128) {
    float s = bf2v[tid];
    for (int k = 0; k < 128; ++k) s += t1[k] * Wf2[k*128 + tid];
    out[tid] = s;
  }
}

// ---------------- launch ----------------
extern "C" void kernel_launch(void* const* d_in, const int* in_sizes, int n_in,
                              void* d_out, int out_size, void* d_ws, size_t ws_size,
                              hipStream_t stream) {
  const float* node_feats = (const float*)d_in[0];
  const float* graph_feats= (const float*)d_in[1];
  const int*   src        = (const int*)d_in[2];
  const int*   dst        = (const int*)d_in[3];
  const float* W_in  = (const float*)d_in[4];
  const float* b_in  = (const float*)d_in[5];
  const float* W_g   = (const float*)d_in[6];
  const float* b_g   = (const float*)d_in[7];
  const float* W_src = (const float*)d_in[8];
  const float* b_src = (const float*)d_in[9];
  const float* W_dst = (const float*)d_in[10];
  const float* b_dst = (const float*)d_in[11];
  const float* attn  = (const float*)d_in[12];
  const float* ln_g  = (const float*)d_in[13];
  const float* ln_b  = (const float*)d_in[14];
  const float* W_f1  = (const float*)d_in[15];
  const float* b_f1  = (const float*)d_in[16];
  const float* W_f2  = (const float*)d_in[17];
  const float* b_f2  = (const float*)d_in[18];

  int N = in_sizes[0] / 64;
  int E = in_sizes[2];

  float* out_f = (float*)d_out;
  float* GEMB  = out_f;              // [128] graph_emb
  float* H     = out_f + 128;        // [N,128] final h (written by last k_edge)

  // ws: pooled | FS8 | FD8 | HB | WB | rowp | bhist | gOff | bucketOff | csrc16
  float*    pooled = (float*)d_ws;
  uchar_t*  FS8 = (uchar_t*)((char*)d_ws + 512);
  uchar_t*  FD8 = FS8 + (size_t)N * 128;
  ushort_t* HB  = (ushort_t*)(FD8 + (size_t)N * 128);
  ushort_t* WB  = HB + (size_t)N * 128;         // 3*32768 elems
  int* ibase = (int*)(WB + 3*32768);
  int* rowp      = ibase;                        // N+1
  int* bhist     = ibase + N + 1;                // NBK*PBLK = 32768
  int* gOff      = bhist + NBK*PBLK;             // 32768
  int* bucketOff = gOff + NBK*PBLK;              // NBK+1
  ushort_t* csrc16 = (ushort_t*)(bucketOff + NBK + 1);  // E
  uint_t* part   = (uint_t*)FS8;  // aliased (spills into FD8): consumed pre-GEMM

  int epb = (E + PBLK - 1) / PBLK;
  int nb  = (N + 511) >> 9;
  int gemm_in_blocks = (N + 63) / 64;

  k_fuse_a<<<305, 256, 0, stream>>>(W_src, W_dst, WB, dst, bhist, E, epb, pooled);
  k_scan2<<<1, 1024, 0, stream>>>(bhist, gOff, bucketOff, E);
  k_fuse_b<<<PBLK + gemm_in_blocks, 256, 0, stream>>>(
      src, dst, gOff, part, E, epb, node_feats, W_in, b_in, HB, N);
  k_csr<<<nb, 512, 0, stream>>>(part, bucketOff, rowp, csrc16, N, E);

  for (int l = 0; l < 3; ++l) {
    k_gemm_mfma<<<(N + 31)/32, 256, 0, stream>>>(
        HB, WB + (size_t)l*32768, b_src + l*128, b_dst + l*128, FS8, FD8, N);
    k_edge<<<2048, 256, 0, stream>>>(
        FS8, FD8, HB, H, rowp, csrc16,
        attn + l*128, ln_g + l*128, ln_b + l*128, (l == 2) ? 1 : 0, N);
  }

  k_pool<<<512, 128, 0, stream>>>(H, pooled, N);
  k_final<<<1, 256, 0, stream>>>(graph_feats, pooled, W_g, b_g, W_f1, b_f1,
                                 W_f2, b_f2, GEMB, 1.0f / (float)N);
}

// Round 16
// 351.510 us; speedup vs baseline: 1.0712x; 1.0712x over previous
//
#include <hip/hip_runtime.h>

typedef unsigned short ushort_t;
typedef unsigned int   uint_t;
typedef unsigned char  uchar_t;
typedef __attribute__((ext_vector_type(8))) __bf16 bf16x8;
typedef __attribute__((ext_vector_type(4))) float   f32x4;

// bf16 helpers (stored bf16, computed f32)
__device__ __forceinline__ float bl(uint_t u){ return __uint_as_float(u<<16); }
__device__ __forceinline__ float bh(uint_t u){ return __uint_as_float(u & 0xffff0000u); }
__device__ __forceinline__ ushort_t f2b(float f){
  uint_t x = __float_as_uint(f);
  return (ushort_t)((x + 0x7fffu + ((x>>16)&1u)) >> 16);   // RTNE
}
__device__ __forceinline__ uint_t pack2(float a, float b){
  return (uint_t)f2b(a) | ((uint_t)f2b(b) << 16);
}

// DPP rotate-reduce over each 16-lane row (VALU-rate, no DS ops)
__device__ __forceinline__ float row_reduce16(float p){
  float t;
  t = __uint_as_float(__builtin_amdgcn_update_dpp(0, __float_as_uint(p), 0x121, 0xf, 0xf, true)); p += t; // row_ror:1
  t = __uint_as_float(__builtin_amdgcn_update_dpp(0, __float_as_uint(p), 0x122, 0xf, 0xf, true)); p += t; // row_ror:2
  t = __uint_as_float(__builtin_amdgcn_update_dpp(0, __float_as_uint(p), 0x124, 0xf, 0xf, true)); p += t; // row_ror:4
  t = __uint_as_float(__builtin_amdgcn_update_dpp(0, __float_as_uint(p), 0x128, 0xf, 0xf, true)); p += t; // row_ror:8
  return p;
}

#define NBK 128          // max dst buckets (bucket = dst >> 9)
#define PBLK 256         // partition blocks

// ------- FUSE_A: blocks [0,48): wswz | [48,304): hist | 304: zero pooled ----
__global__ __launch_bounds__(256) void k_fuse_a(
    const float* __restrict__ Wsrc, const float* __restrict__ Wdst,
    ushort_t* __restrict__ WB,
    const int* __restrict__ dst, int* __restrict__ bhist, int E, int epb,
    float* __restrict__ pooled)
{
  int blk = blockIdx.x;
  if (blk < 48) {                    // weight pre-swizzle (12288 threads exact)
    int t = blk*256 + threadIdx.x;
    int l = t >> 12;
    int rem = t & 4095;
    int ct = rem >> 8;
    int kc = (rem >> 6) & 3;
    int lane = rem & 63;
    int n = ct*16 + (lane & 15);
    int kbase = kc*32 + (lane >> 4)*8;
    const float* Wp; int nn;
    if (n < 128) { Wp = Wsrc + l*16384; nn = n; }
    else         { Wp = Wdst + l*16384; nn = n - 128; }
    uint4 o;
    o.x = pack2(Wp[(kbase+0)*128+nn], Wp[(kbase+1)*128+nn]);
    o.y = pack2(Wp[(kbase+2)*128+nn], Wp[(kbase+3)*128+nn]);
    o.z = pack2(Wp[(kbase+4)*128+nn], Wp[(kbase+5)*128+nn]);
    o.w = pack2(Wp[(kbase+6)*128+nn], Wp[(kbase+7)*128+nn]);
    *(uint4*)&WB[(size_t)t * 8] = o;
  } else if (blk < 304) {            // bucket histogram
    __shared__ int lh[NBK];
    int b2 = blk - 48, t = threadIdx.x;
    if (t < NBK) lh[t] = 0;
    __syncthreads();
    int s = b2*epb, e = s + epb; if (e > E) e = E;
    for (int i = s + t; i < e; i += 256)
      atomicAdd(&lh[dst[i] >> 9], 1);
    __syncthreads();
    if (t < NBK) bhist[t*PBLK + b2] = lh[t];   // bucket-major
  } else {
    if (threadIdx.x < 128) pooled[threadIdx.x] = 0.f;
  }
}

// ------- CSR stage 2: scan (bucket,block) hist -> gOff, bucketOff -----------
__global__ __launch_bounds__(1024) void k_scan2(
    const int* __restrict__ bhist, int* __restrict__ gOff,
    int* __restrict__ bucketOff, int E)
{
  __shared__ int sums[1024];
  int tid = threadIdx.x;
  int s0 = tid * 32;                 // 32768 entries, 32 per thread
  int local = 0;
  #pragma unroll
  for (int i = 0; i < 32; ++i) local += bhist[s0 + i];
  sums[tid] = local;
  __syncthreads();
  for (int off = 1; off < 1024; off <<= 1) {
    int v = (tid >= off) ? sums[tid - off] : 0;
    __syncthreads();
    sums[tid] += v;
    __syncthreads();
  }
  int run = (tid == 0) ? 0 : sums[tid - 1];
  #pragma unroll
  for (int i = 0; i < 32; ++i) { gOff[s0 + i] = run; run += bhist[s0 + i]; }
  __syncthreads();
  if (tid < NBK) bucketOff[tid] = gOff[tid*PBLK];
  if (tid == NBK) bucketOff[NBK] = E;
}

// ------- FUSE_B: blocks [0,PBLK): partition | rest: input GEMM --------------
__global__ __launch_bounds__(256) void k_fuse_b(
    const int* __restrict__ src, const int* __restrict__ dst,
    const int* __restrict__ gOff, uint_t* __restrict__ part, int E, int epb,
    const float* __restrict__ nf, const float* __restrict__ W,
    const float* __restrict__ b, ushort_t* __restrict__ HB, int N)
{
  __shared__ int loff[NBK];
  __shared__ float sA[64*64];
  if (blockIdx.x < PBLK) {           // edge partition into dst-buckets
    int blk = blockIdx.x, t = threadIdx.x;
    if (t < NBK) loff[t] = gOff[t*PBLK + blk];
    __syncthreads();
    int s = blk*epb, e = s + epb; if (e > E) e = E;
    for (int i = s + t; i < e; i += 256) {
      int d = dst[i];
      int bb = d >> 9;
      int p = atomicAdd(&loff[bb], 1);
      part[p] = (uint_t)src[i] | ((uint_t)(d & 511) << 16);
    }
  } else {                           // HB = bf16( nf @ W_in + b_in )
    int row0 = (blockIdx.x - PBLK) * 64;
    int tid = threadIdx.x;
    {
      int q = tid;
      #pragma unroll
      for (int j = 0; j < 4; ++j, q += 256) {
        int r = q >> 4;
        int c = (q & 15) << 2;
        float4 v = make_float4(0.f,0.f,0.f,0.f);
        if (row0 + r < N) v = *(const float4*)&nf[(size_t)(row0 + r)*64 + c];
        *(float4*)&sA[r*64 + c] = v;
      }
    }
    __syncthreads();
    int cg = tid & 15, rg = tid >> 4;
    int c0 = cg * 8;
    float acc[4][8];
    #pragma unroll
    for (int i = 0; i < 4; ++i)
      #pragma unroll
      for (int j = 0; j < 8; ++j) acc[i][j] = 0.f;
    for (int k = 0; k < 64; ++k) {
      float4 wa = *(const float4*)&W[k*128 + c0];
      float4 wb = *(const float4*)&W[k*128 + c0 + 4];
      float w[8] = {wa.x,wa.y,wa.z,wa.w,wb.x,wb.y,wb.z,wb.w};
      float hv[4];
      #pragma unroll
      for (int i = 0; i < 4; ++i) hv[i] = sA[(rg*4 + i)*64 + k];
      #pragma unroll
      for (int i = 0; i < 4; ++i)
        #pragma unroll
        for (int j = 0; j < 8; ++j) acc[i][j] += hv[i]*w[j];
    }
    float4 b1 = *(const float4*)&b[c0];
    float4 b2 = *(const float4*)&b[c0 + 4];
    float bb[8] = {b1.x,b1.y,b1.z,b1.w,b2.x,b2.y,b2.z,b2.w};
    #pragma unroll
    for (int i = 0; i < 4; ++i) {
      int row = row0 + rg*4 + i;
      if (row < N) {
        uint4 hb;
        hb.x = pack2(acc[i][0]+bb[0], acc[i][1]+bb[1]);
        hb.y = pack2(acc[i][2]+bb[2], acc[i][3]+bb[3]);
        hb.z = pack2(acc[i][4]+bb[4], acc[i][5]+bb[5]);
        hb.w = pack2(acc[i][6]+bb[6], acc[i][7]+bb[7]);
        *(uint4*)&HB[(size_t)row*128 + c0] = hb;
      }
    }
  }
}

// ------- CSR stage 4: count+scan+rowp+place; store u16 src row indices ------
__global__ __launch_bounds__(512) void k_csr(
    const uint_t* __restrict__ part, const int* __restrict__ bucketOff,
    int* __restrict__ rowp, ushort_t* __restrict__ csrc16, int N, int E)
{
  __shared__ int lcnt[512];
  __shared__ int lpos[512];
  int b = blockIdx.x, t = threadIdx.x;
  int base = b << 9;
  int cnt = N - base; if (cnt > 512) cnt = 512;
  lcnt[t] = 0;
  __syncthreads();
  int s = bucketOff[b], e = bucketOff[b + 1];
  for (int i = s + t; i < e; i += 512)
    atomicAdd(&lcnt[part[i] >> 16], 1);
  __syncthreads();
  int v = lcnt[t];
  lpos[t] = v;
  __syncthreads();
  for (int off = 1; off < 512; off <<= 1) {       // inclusive scan
    int u = (t >= off) ? lpos[t - off] : 0;
    __syncthreads();
    lpos[t] += u;
    __syncthreads();
  }
  int rp = s + lpos[t] - v;                       // exclusive prefix + bucket base
  if (t < cnt) rowp[base + t] = rp;
  if (b == 0 && t == 0) rowp[N] = E;
  __syncthreads();
  lpos[t] = rp;
  __syncthreads();
  for (int i = s + t; i < e; i += 512) {
    uint_t pr = part[i];
    int p = atomicAdd(&lpos[pr >> 16], 1);
    csrc16[p] = (ushort_t)(pr & 0xffffu);         // row index; <<7 at use site
  }
}

// ------- layer GEMM via MFMA: FS8 / FD8 = fp8( HB @ W + b ), symmetric ------
__global__ __launch_bounds__(256) void k_gemm_mfma(
    const ushort_t* __restrict__ HB, const ushort_t* __restrict__ WB,
    const float* __restrict__ bsrc, const float* __restrict__ bdst,
    uchar_t* __restrict__ FS8, uchar_t* __restrict__ FD8, int N)
{
  int m0 = blockIdx.x * 32;
  int tid = threadIdx.x;
  int w = tid >> 6, lane = tid & 63;
  int lrow = lane & 15, lk = lane >> 4;

  bf16x8 a[2][4];
  #pragma unroll
  for (int rt = 0; rt < 2; ++rt) {
    int row = m0 + rt*16 + lrow;
    if (row > N-1) row = N-1;
    #pragma unroll
    for (int kc = 0; kc < 4; ++kc)
      a[rt][kc] = *(const bf16x8*)&HB[(size_t)row*128 + kc*32 + lk*8];
  }

  #pragma unroll
  for (int c = 0; c < 4; ++c) {
    int ct = w*4 + c;
    int n = ct*16 + lrow;
    bf16x8 bfr[4];
    #pragma unroll
    for (int kc = 0; kc < 4; ++kc)
      bfr[kc] = *(const bf16x8*)&WB[((size_t)(ct*4 + kc)*64 + lane) * 8];
    int nn = n & 127;
    uchar_t* OUT = (ct < 8) ? FS8 : FD8;
    float bias = (ct < 8) ? bsrc[nn] : bdst[nn];
    #pragma unroll
    for (int rt = 0; rt < 2; ++rt) {
      f32x4 acc = {0.f, 0.f, 0.f, 0.f};
      #pragma unroll
      for (int kc = 0; kc < 4; ++kc)
        acc = __builtin_amdgcn_mfma_f32_16x16x32_bf16(a[rt][kc], bfr[kc], acc, 0, 0, 0);
      int r = m0 + rt*16 + lk*4;        // C/D: col=lane&15, row=(lane>>4)*4+reg
      int w01 = __builtin_amdgcn_cvt_pk_fp8_f32(acc[0]+bias, acc[1]+bias, 0, false);
      int w23 = __builtin_amdgcn_cvt_pk_fp8_f32(acc[2]+bias, acc[3]+bias, 0, false);
      if (r     < N) OUT[(size_t)(r    )*128 + nn] = (uchar_t)(w01);
      if (r + 1 < N) OUT[(size_t)(r + 1)*128 + nn] = (uchar_t)(w01 >> 8);
      if (r + 2 < N) OUT[(size_t)(r + 2)*128 + nn] = (uchar_t)(w23);
      if (r + 3 < N) OUT[(size_t)(r + 3)*128 + nn] = (uchar_t)(w23 >> 8);
    }
  }
}

// ------- fused edge aggregate + softmax + residual + LN + ReLU ---------------
// r12-proven structure: quad-parallel lanes, DPP reduce, 4 QM chains/iter,
// double-buffered 16-edge prefetch. fp8 FD + u16 csrc (fewer miss bytes).
__global__ __launch_bounds__(256) void k_edge(
    const uchar_t* __restrict__ FS8, const uchar_t* __restrict__ FD8,
    ushort_t* __restrict__ HB, float* __restrict__ H,
    const int* __restrict__ rowp, const ushort_t* __restrict__ csrc16,
    const float* __restrict__ attn, const float* __restrict__ lng,
    const float* __restrict__ lnb, int last, int N)
{
  int node = __builtin_amdgcn_readfirstlane(blockIdx.x * 4 + (threadIdx.x >> 6));
  if (node >= N) return;
  int lane = threadIdx.x & 63;
  int g = lane >> 4;                 // edge slot within quad (== DPP row id)
  int c = lane & 15;                 // channel chunk
  int cb = c << 3;                   // channel base (fp8 byte offset)

  float fdv[8], av6[8], av4[8];
  {
    uint2 fdu = *(const uint2*)((const char*)FD8 + node*128 + cb);
    auto f01 = __builtin_amdgcn_cvt_pk_f32_fp8((int)fdu.x, false);
    auto f23 = __builtin_amdgcn_cvt_pk_f32_fp8((int)fdu.x, true);
    auto f45 = __builtin_amdgcn_cvt_pk_f32_fp8((int)fdu.y, false);
    auto f67 = __builtin_amdgcn_cvt_pk_f32_fp8((int)fdu.y, true);
    fdv[0]=f01[0]; fdv[1]=f01[1]; fdv[2]=f23[0]; fdv[3]=f23[1];
    fdv[4]=f45[0]; fdv[5]=f45[1]; fdv[6]=f67[0]; fdv[7]=f67[1];
    float4 a1 = *(const float4*)&attn[cb];
    float4 a2 = *(const float4*)&attn[cb + 4];
    float aa[8] = {a1.x,a1.y,a1.z,a1.w,a2.x,a2.y,a2.z,a2.w};
    #pragma unroll
    for (int k = 0; k < 8; ++k) {
      av6[k] = aa[k] * 0.865617024f;   // 0.6 * log2(e)
      av4[k] = aa[k] * 0.577078016f;   // 0.4 * log2(e)
    }
  }
  int beg = __builtin_amdgcn_readfirstlane(rowp[node]);
  int end = __builtin_amdgcn_readfirstlane(rowp[node + 1]);   // deg >= 1
  int deg = end - beg;
  int npair = deg >> 4, ntail = deg & 15;
  int tb = beg + (npair << 4);
  int endm1 = end - 1;

  float den = 0.f;
  float acc[8];
  #pragma unroll
  for (int k = 0; k < 8; ++k) acc[k] = 0.f;

  uint2 a0,a1q,a2q,a3q, b0,b1q,b2q,b3q, t0,t1q,t2q,t3q;

  #define PREF(bu0, bu1, kb) {                                              \
    int s0 = ((int)csrc16[(kb) + g]) << 7;                                  \
    int s1 = ((int)csrc16[(kb) + 4 + g]) << 7;                              \
    bu0 = *(const uint2*)((const char*)FS8 + s0 + cb);                      \
    bu1 = *(const uint2*)((const char*)FS8 + s1 + cb);                      \
  }

  #define PREFT(bu0, bu1, kb) {                                             \
    int i0 = (kb) + g;     i0 = (i0 < endm1) ? i0 : endm1;                  \
    int i1 = (kb) + 4 + g; i1 = (i1 < endm1) ? i1 : endm1;                  \
    bu0 = *(const uint2*)((const char*)FS8 + (((int)csrc16[i0]) << 7) + cb);\
    bu1 = *(const uint2*)((const char*)FS8 + (((int)csrc16[i1]) << 7) + cb);\
  }

  #define QM(u, MASKED, kbq) {                                              \
    float cf[8];                                                            \
    { auto p01 = __builtin_amdgcn_cvt_pk_f32_fp8((int)(u).x, false);        \
      auto p23 = __builtin_amdgcn_cvt_pk_f32_fp8((int)(u).x, true);         \
      auto p45 = __builtin_amdgcn_cvt_pk_f32_fp8((int)(u).y, false);        \
      auto p67 = __builtin_amdgcn_cvt_pk_f32_fp8((int)(u).y, true);         \
      cf[0]=p01[0]; cf[1]=p01[1]; cf[2]=p23[0]; cf[3]=p23[1];               \
      cf[4]=p45[0]; cf[5]=p45[1]; cf[6]=p67[0]; cf[7]=p67[1]; }             \
    float p = 0.f;                                                          \
    _Pragma("unroll")                                                       \
    for (int k = 0; k < 8; ++k) {                                           \
      float x = cf[k] + fdv[k];                                             \
      p = fmaf(x, av6[k], p);                                               \
      p = fmaf(fabsf(x), av4[k], p);                                        \
    }                                                                       \
    p = row_reduce16(p);                                                    \
    float ex = __builtin_amdgcn_exp2f(p);                                   \
    if (MASKED) ex = ((kbq) + g < end) ? ex : 0.f;                          \
    den += ex;                                                              \
    _Pragma("unroll")                                                       \
    for (int k = 0; k < 8; ++k) acc[k] = fmaf(ex, cf[k], acc[k]);           \
  }

  if (ntail) { PREFT(t0, t1q, tb) PREFT(t2q, t3q, tb + 8) }
  if (npair) {
    PREF(a0, a1q, beg) PREF(a2q, a3q, beg + 8)
    int rem2 = npair, kb = beg + 16;
    for (;;) {
      if (rem2 > 1) { PREF(b0, b1q, kb) PREF(b2q, b3q, kb + 8) }
      QM(a0, 0, 0) QM(a1q, 0, 0) QM(a2q, 0, 0) QM(a3q, 0, 0)
      if (--rem2 == 0) break;
      kb += 16;
      if (rem2 > 1) { PREF(a0, a1q, kb) PREF(a2q, a3q, kb + 8) }
      QM(b0, 0, 0) QM(b1q, 0, 0) QM(b2q, 0, 0) QM(b3q, 0, 0)
      if (--rem2 == 0) break;
      kb += 16;
    }
  }
  if (ntail) {
    QM(t0, 1, tb) QM(t1q, 1, tb + 4) QM(t2q, 1, tb + 8) QM(t3q, 1, tb + 12)
  }
  #undef PREF
  #undef PREFT
  #undef QM

  // combine the 4 edge-slot partials (cross-row shuffles, once per node)
  den += __shfl_xor(den, 16); den += __shfl_xor(den, 32);
  #pragma unroll
  for (int k = 0; k < 8; ++k) {
    acc[k] += __shfl_xor(acc[k], 16);
    acc[k] += __shfl_xor(acc[k], 32);
  }
  float rden = 1.f / den;            // deg >= 1 -> den > 0

  // residual + LN + ReLU (each lane owns its 8 channels; groups redundant)
  float x[8];
  {
    uint4 hu = *(const uint4*)((const char*)HB + node*256 + (cb << 1));
    float hb[8] = {bl(hu.x),bh(hu.x),bl(hu.y),bh(hu.y),
                   bl(hu.z),bh(hu.z),bl(hu.w),bh(hu.w)};
    #pragma unroll
    for (int k = 0; k < 8; ++k) x[k] = 2.f*hb[k] + acc[k]*rden;
  }
  float s = 0.f;
  #pragma unroll
  for (int k = 0; k < 8; ++k) s += x[k];
  s = row_reduce16(s);
  float mean = s * (1.f/128.f);
  float v = 0.f;
  #pragma unroll
  for (int k = 0; k < 8; ++k) { x[k] -= mean; v += x[k]*x[k]; }
  v = row_reduce16(v);
  float rs = rsqrtf(v * (1.f/128.f) + 1e-5f);
  float4 g1 = *(const float4*)&lng[cb];
  float4 g2 = *(const float4*)&lng[cb + 4];
  float4 be1 = *(const float4*)&lnb[cb];
  float4 be2 = *(const float4*)&lnb[cb + 4];
  float gv[8] = {g1.x,g1.y,g1.z,g1.w,g2.x,g2.y,g2.z,g2.w};
  float bv[8] = {be1.x,be1.y,be1.z,be1.w,be2.x,be2.y,be2.z,be2.w};
  float y[8];
  #pragma unroll
  for (int k = 0; k < 8; ++k) y[k] = fmaxf(x[k]*rs*gv[k] + bv[k], 0.f);

  if (lane < 16) {                   // one group writes
    if (last) {
      float4 o1 = make_float4(y[0],y[1],y[2],y[3]);
      float4 o2 = make_float4(y[4],y[5],y[6],y[7]);
      *(float4*)((char*)H + node*512 + (cb << 2))      = o1;
      *(float4*)((char*)H + node*512 + (cb << 2) + 16) = o2;
    } else {
      uint4 o;
      o.x = pack2(y[0],y[1]); o.y = pack2(y[2],y[3]);
      o.z = pack2(y[4],y[5]); o.w = pack2(y[6],y[7]);
      *(uint4*)((char*)HB + node*256 + (cb << 1)) = o;
    }
  }
}

// ---------------- pooled mean partials ----------------
__global__ __launch_bounds__(128) void k_pool(const float* __restrict__ H,
                                              float* __restrict__ pooled, int N){
  int c = threadIdx.x;
  float s = 0.f;
  for (int r = blockIdx.x; r < N; r += gridDim.x) s += H[(size_t)r*128 + c];
  atomicAdd(&pooled[c], s);
}

// ---------------- final head ----------------
__global__ __launch_bounds__(256) void k_final(
    const float* __restrict__ gf, const float* __restrict__ pooled,
    const float* __restrict__ Wg, const float* __restrict__ bg,
    const float* __restrict__ Wf1, const float* __restrict__ bf1,
    const float* __restrict__ Wf2, const float* __restrict__ bf2v,
    float* __restrict__ out, float inv_n)
{
  __shared__ float comb[256];
  __shared__ float t1[128];
  int tid = threadIdx.x;
  if (tid < 128) {
    comb[tid] = pooled[tid] * inv_n;
  } else {
    int c = tid - 128;
    float s = bg[c];
    for (int k = 0; k < 32; ++k) s += gf[k] * Wg[k*128 + c];
    comb[128 + c] = s;
  }
  __syncthreads();
  if (tid < 128) {
    float s = bf1[tid];
    for (int k = 0; k < 256; ++k) s += comb[k] * Wf1[k*128 + tid];
    t1[tid] = fmaxf(s, 0.f);
  }
  __syncthreads();
  if (tid < 128) {
    float s = bf2v[tid];
    for (int k = 0; k < 128; ++k) s += t1[k] * Wf2[k*128 + tid];
    out[tid] = s;
  }
}

// ---------------- launch ----------------
extern "C" void kernel_launch(void* const* d_in, const int* in_sizes, int n_in,
                              void* d_out, int out_size, void* d_ws, size_t ws_size,
                              hipStream_t stream) {
  const float* node_feats = (const float*)d_in[0];
  const float* graph_feats= (const float*)d_in[1];
  const int*   src        = (const int*)d_in[2];
  const int*   dst        = (const int*)d_in[3];
  const float* W_in  = (const float*)d_in[4];
  const float* b_in  = (const float*)d_in[5];
  const float* W_g   = (const float*)d_in[6];
  const float* b_g   = (const float*)d_in[7];
  const float* W_src = (const float*)d_in[8];
  const float* b_src = (const float*)d_in[9];
  const float* W_dst = (const float*)d_in[10];
  const float* b_dst = (const float*)d_in[11];
  const float* attn  = (const float*)d_in[12];
  const float* ln_g  = (const float*)d_in[13];
  const float* ln_b  = (const float*)d_in[14];
  const float* W_f1  = (const float*)d_in[15];
  const float* b_f1  = (const float*)d_in[16];
  const float* W_f2  = (const float*)d_in[17];
  const float* b_f2  = (const float*)d_in[18];

  int N = in_sizes[0] / 64;
  int E = in_sizes[2];

  float* out_f = (float*)d_out;
  float* GEMB  = out_f;              // [128] graph_emb
  float* H     = out_f + 128;        // [N,128] final h (written by last k_edge)

  // ws: pooled | FS8 | FD8 | HB | WB | rowp | bhist | gOff | bucketOff | csrc16
  float*    pooled = (float*)d_ws;
  uchar_t*  FS8 = (uchar_t*)((char*)d_ws + 512);
  uchar_t*  FD8 = FS8 + (size_t)N * 128;
  ushort_t* HB  = (ushort_t*)(FD8 + (size_t)N * 128);
  ushort_t* WB  = HB + (size_t)N * 128;         // 3*32768 elems
  int* ibase = (int*)(WB + 3*32768);
  int* rowp      = ibase;                        // N+1
  int* bhist     = ibase + N + 1;                // NBK*PBLK = 32768
  int* gOff      = bhist + NBK*PBLK;             // 32768
  int* bucketOff = gOff + NBK*PBLK;              // NBK+1
  ushort_t* csrc16 = (ushort_t*)(bucketOff + NBK + 1);  // E
  uint_t* part   = (uint_t*)FS8;  // aliased (spills into FD8): consumed pre-GEMM

  int epb = (E + PBLK - 1) / PBLK;
  int nb  = (N + 511) >> 9;
  int gemm_in_blocks = (N + 63) / 64;

  k_fuse_a<<<305, 256, 0, stream>>>(W_src, W_dst, WB, dst, bhist, E, epb, pooled);
  k_scan2<<<1, 1024, 0, stream>>>(bhist, gOff, bucketOff, E);
  k_fuse_b<<<PBLK + gemm_in_blocks, 256, 0, stream>>>(
      src, dst, gOff, part, E, epb, node_feats, W_in, b_in, HB, N);
  k_csr<<<nb, 512, 0, stream>>>(part, bucketOff, rowp, csrc16, N, E);

  for (int l = 0; l < 3; ++l) {
    k_gemm_mfma<<<(N + 31)/32, 256, 0, stream>>>(
        HB, WB + (size_t)l*32768, b_src + l*128, b_dst + l*128, FS8, FD8, N);
    k_edge<<<(N + 3)/4, 256, 0, stream>>>(
        FS8, FD8, HB, H, rowp, csrc16,
        attn + l*128, ln_g + l*128, ln_b + l*128, (l == 2) ? 1 : 0, N);
  }

  k_pool<<<512, 128, 0, stream>>>(H, pooled, N);
  k_final<<<1, 256, 0, stream>>>(graph_feats, pooled, W_g, b_g, W_f1, b_f1,
                                 W_f2, b_f2, GEMB, 1.0f / (float)N);
}